// Round 3
// baseline (1580.058 us; speedup 1.0000x reference)
//
#include <hip/hip_runtime.h>
#include <cmath>

// Problem constants (match reference)
#define NN 20000     // N_NODES
#define NP 100000    // N_PATHS
#define D  128       // D_IN == H
#define G4 512       // 4*H gate width
#define NG 128       // N_GRAPHS
#define NC 10        // N_CLASSES
#define CHUNK 20000  // path_3 processing chunk

__device__ __forceinline__ float sigf(float x) { return 1.0f / (1.0f + expf(-x)); }

// ---------------------------------------------------------------------------
// GEMM: C[M,N] = A[M,128] @ W[N,128]^T (+bias[N]) (optional relu). K=128 fixed.
// 128x128 block tile, 256 threads, 8x8 per thread (8 FLOP per LDS float).
// K in two 64-chunks, single LDS buffer (64KB -> 2 blocks/CU), chunk-1
// prefetched to registers during chunk-0 compute.
// LDS layout: float4 slot(r,c4) = r*16 + (c4 ^ ((r>>3)&7)) — XOR swizzle:
// A-reads broadcast conflict-free, W-reads at the structural 2-way minimum.
// ---------------------------------------------------------------------------
__global__ __launch_bounds__(256) void gemm128(
    const float* __restrict__ A, const float* __restrict__ W,
    const float* __restrict__ bias, float* __restrict__ C,
    int M, int N, int relu)
{
  __shared__ float4 As4[2048];  // 128 rows x 16 float4 (64 K-floats)
  __shared__ float4 Ws4[2048];

  const int tid = threadIdx.x;
  const int bm = blockIdx.x * 128;
  const int bn = blockIdx.y * 128;

  const int ty = tid >> 4;        // 0..15
  const int tx = tid & 15;        // 0..15
  const int tm = ty * 8;
  const int tn = tx * 8;
  const int axor = ty & 7;        // (tm>>3)&7
  const int wxor = tx & 7;        // (tn>>3)&7

  const int sr = tid >> 4;        // staging row within 16-row group
  const int sc = tid & 15;        // staging float4-col 0..15

  // ---- stage chunk 0 (k = 0..63) ----
#pragma unroll
  for (int pass = 0; pass < 8; ++pass) {
    int r = pass * 16 + sr;
    int sw = sc ^ ((r >> 3) & 7);
    int ga = bm + r; ga = ga < M ? ga : M - 1;
    As4[r * 16 + sw] = *(const float4*)(A + (size_t)ga * 128 + sc * 4);
    int gw = bn + r; gw = gw < N ? gw : N - 1;
    Ws4[r * 16 + sw] = *(const float4*)(W + (size_t)gw * 128 + sc * 4);
  }

  // ---- prefetch chunk 1 (k = 64..127) into registers ----
  float4 pa[8], pw[8];
#pragma unroll
  for (int pass = 0; pass < 8; ++pass) {
    int r = pass * 16 + sr;
    int ga = bm + r; ga = ga < M ? ga : M - 1;
    pa[pass] = *(const float4*)(A + (size_t)ga * 128 + 64 + sc * 4);
    int gw = bn + r; gw = gw < N ? gw : N - 1;
    pw[pass] = *(const float4*)(W + (size_t)gw * 128 + 64 + sc * 4);
  }

  float acc[8][8] = {};

  __syncthreads();

  // ---- compute chunk 0 ----
#pragma unroll 2
  for (int k4 = 0; k4 < 16; ++k4) {
    float4 av[8], wv[8];
#pragma unroll
    for (int i = 0; i < 8; ++i) av[i] = As4[(tm + i) * 16 + (k4 ^ axor)];
#pragma unroll
    for (int j = 0; j < 8; ++j) wv[j] = Ws4[(tn + j) * 16 + (k4 ^ wxor)];
#pragma unroll
    for (int i = 0; i < 8; ++i)
#pragma unroll
      for (int j = 0; j < 8; ++j) {
        acc[i][j] = fmaf(av[i].x, wv[j].x, acc[i][j]);
        acc[i][j] = fmaf(av[i].y, wv[j].y, acc[i][j]);
        acc[i][j] = fmaf(av[i].z, wv[j].z, acc[i][j]);
        acc[i][j] = fmaf(av[i].w, wv[j].w, acc[i][j]);
      }
  }

  __syncthreads();

  // ---- write chunk 1 to LDS ----
#pragma unroll
  for (int pass = 0; pass < 8; ++pass) {
    int r = pass * 16 + sr;
    int sw = sc ^ ((r >> 3) & 7);
    As4[r * 16 + sw] = pa[pass];
    Ws4[r * 16 + sw] = pw[pass];
  }

  __syncthreads();

  // ---- compute chunk 1 ----
#pragma unroll 2
  for (int k4 = 0; k4 < 16; ++k4) {
    float4 av[8], wv[8];
#pragma unroll
    for (int i = 0; i < 8; ++i) av[i] = As4[(tm + i) * 16 + (k4 ^ axor)];
#pragma unroll
    for (int j = 0; j < 8; ++j) wv[j] = Ws4[(tn + j) * 16 + (k4 ^ wxor)];
#pragma unroll
    for (int i = 0; i < 8; ++i)
#pragma unroll
      for (int j = 0; j < 8; ++j) {
        acc[i][j] = fmaf(av[i].x, wv[j].x, acc[i][j]);
        acc[i][j] = fmaf(av[i].y, wv[j].y, acc[i][j]);
        acc[i][j] = fmaf(av[i].z, wv[j].z, acc[i][j]);
        acc[i][j] = fmaf(av[i].w, wv[j].w, acc[i][j]);
      }
  }

  // ---- epilogue ----
#pragma unroll
  for (int i = 0; i < 8; ++i) {
    int r = bm + tm + i;
    if (r >= M) continue;
#pragma unroll
    for (int j = 0; j < 8; ++j) {
      int cn = bn + tn + j;
      if (cn >= N) continue;
      float v = acc[i][j] + (bias ? bias[cn] : 0.f);
      if (relu) v = fmaxf(v, 0.f);
      C[(size_t)r * N + cn] = v;
    }
  }
}

// ---------------------------------------------------------------------------
// BatchNorm helpers
// ---------------------------------------------------------------------------
__global__ void zero_kernel(float* p, int n) {
  for (int i = blockIdx.x * blockDim.x + threadIdx.x; i < n; i += gridDim.x * blockDim.x)
    p[i] = 0.f;
}

__global__ void addvec_kernel(const float* a, const float* b, float* o, int n) {
  int i = blockIdx.x * blockDim.x + threadIdx.x;
  if (i < n) o[i] = a[i] + b[i];
}

__global__ __launch_bounds__(256) void bn_stats(const float* __restrict__ u,
                                                float* __restrict__ stats,
                                                int M, int rowsPerBlock) {
  __shared__ float sh[512];
  const int j = threadIdx.x & 127;
  const int half = threadIdx.x >> 7;
  int r0 = blockIdx.x * rowsPerBlock;
  int r1 = min(M, r0 + rowsPerBlock);
  float s = 0.f, q = 0.f;
  for (int r = r0 + half; r < r1; r += 2) {
    float v = u[(size_t)r * 128 + j];
    s += v; q += v * v;
  }
  sh[threadIdx.x] = s;
  sh[256 + threadIdx.x] = q;
  __syncthreads();
  if (threadIdx.x < 128) {
    atomicAdd(&stats[j], sh[j] + sh[j + 128]);
    atomicAdd(&stats[128 + j], sh[256 + j] + sh[256 + j + 128]);
  }
}

// float4-vectorized apply+relu
__global__ void bn_apply_relu(const float* __restrict__ u, const float* __restrict__ stats,
                              const float* __restrict__ g, const float* __restrict__ b,
                              float* __restrict__ out, int n4, float invM) {
  int idx = blockIdx.x * blockDim.x + threadIdx.x;
  if (idx >= n4) return;
  int q = idx & 31;
  float4 uv = ((const float4*)u)[idx];
  float4 sv = ((const float4*)stats)[q];
  float4 qv = ((const float4*)stats)[32 + q];
  float4 gv = ((const float4*)g)[q];
  float4 bv = ((const float4*)b)[q];
  float4 o;
  {
    float m = sv.x * invM, var = qv.x * invM - m * m;
    o.x = fmaxf(gv.x * (uv.x - m) * rsqrtf(var + 1e-5f) + bv.x, 0.f);
  }
  {
    float m = sv.y * invM, var = qv.y * invM - m * m;
    o.y = fmaxf(gv.y * (uv.y - m) * rsqrtf(var + 1e-5f) + bv.y, 0.f);
  }
  {
    float m = sv.z * invM, var = qv.z * invM - m * m;
    o.z = fmaxf(gv.z * (uv.z - m) * rsqrtf(var + 1e-5f) + bv.z, 0.f);
  }
  {
    float m = sv.w * invM, var = qv.w * invM - m * m;
    o.w = fmaxf(gv.w * (uv.w - m) * rsqrtf(var + 1e-5f) + bv.w, 0.f);
  }
  ((float4*)out)[idx] = o;
}

// ---------------------------------------------------------------------------
// LSTM pieces (gate order i,f,g,o at float4-offsets 0,32,64,96 per node row).
// All float4-vectorized: one thread = 4 channels.
// ---------------------------------------------------------------------------
__global__ void lstm_step0(const float* __restrict__ Z, float* __restrict__ H1,
                           float* __restrict__ C1, int n4) {
  int idx = blockIdx.x * blockDim.x + threadIdx.x;
  if (idx >= n4) return;
  int v = idx >> 5, q = idx & 31;
  const float4* z = (const float4*)(Z + (size_t)v * G4);
  float4 zi = z[q], zg = z[64 + q], zo = z[96 + q];
  float4 c, h;
  c.x = sigf(zi.x) * tanhf(zg.x); h.x = sigf(zo.x) * tanhf(c.x);
  c.y = sigf(zi.y) * tanhf(zg.y); h.y = sigf(zo.y) * tanhf(c.y);
  c.z = sigf(zi.z) * tanhf(zg.z); h.z = sigf(zo.z) * tanhf(c.z);
  c.w = sigf(zi.w) * tanhf(zg.w); h.w = sigf(zo.w) * tanhf(c.w);
  ((float4*)C1)[idx] = c;
  ((float4*)H1)[idx] = h;
}

__device__ __forceinline__ void lstm_gate4(const float4 zi, const float4 zf,
                                           const float4 zg, const float4 zo,
                                           const float4 ri, const float4 rf,
                                           const float4 rg, const float4 ro,
                                           const float4 cin, float4* cout, float4* hout) {
  float c, out;
  c = sigf(zf.x + rf.x) * cin.x + sigf(zi.x + ri.x) * tanhf(zg.x + rg.x);
  out = sigf(zo.x + ro.x) * tanhf(c); cout->x = c; hout->x = out;
  c = sigf(zf.y + rf.y) * cin.y + sigf(zi.y + ri.y) * tanhf(zg.y + rg.y);
  out = sigf(zo.y + ro.y) * tanhf(c); cout->y = c; hout->y = out;
  c = sigf(zf.z + rf.z) * cin.z + sigf(zi.z + ri.z) * tanhf(zg.z + rg.z);
  out = sigf(zo.z + ro.z) * tanhf(c); cout->z = c; hout->z = out;
  c = sigf(zf.w + rf.w) * cin.w + sigf(zi.w + ri.w) * tanhf(zg.w + rg.w);
  out = sigf(zo.w + ro.w) * tanhf(c); cout->w = c; hout->w = out;
}

// T=2 final: gates = Z[b] + R1[a]; hf -> scatter-add agg[b]
__global__ void lstm_final2(const int* __restrict__ path, const float* __restrict__ Z,
                            const float* __restrict__ R1, const float* __restrict__ C1,
                            float* __restrict__ agg, int n4) {
  int idx = blockIdx.x * blockDim.x + threadIdx.x;
  if (idx >= n4) return;
  int p = idx >> 5, q = idx & 31;
  int a = path[p * 2 + 0], b = path[p * 2 + 1];
  const float4* z = (const float4*)(Z + (size_t)b * G4);
  const float4* r = (const float4*)(R1 + (size_t)a * G4);
  float4 cin = ((const float4*)(C1 + (size_t)a * D))[q];
  float4 c, h;
  lstm_gate4(z[q], z[32 + q], z[64 + q], z[96 + q],
             r[q], r[32 + q], r[64 + q], r[96 + q], cin, &c, &h);
  float* dst = agg + (size_t)b * D + q * 4;
  atomicAdd(dst + 0, h.x); atomicAdd(dst + 1, h.y);
  atomicAdd(dst + 2, h.z); atomicAdd(dst + 3, h.w);
}

// T=3 middle: store h2,c2 per path-local
__global__ void lstm_step1(const int* __restrict__ path, const float* __restrict__ Z,
                           const float* __restrict__ R1, const float* __restrict__ C1,
                           float* __restrict__ h2, float* __restrict__ c2, int n4) {
  int idx = blockIdx.x * blockDim.x + threadIdx.x;
  if (idx >= n4) return;
  int p = idx >> 5, q = idx & 31;
  int a = path[p * 3 + 0], b = path[p * 3 + 1];
  const float4* z = (const float4*)(Z + (size_t)b * G4);
  const float4* r = (const float4*)(R1 + (size_t)a * G4);
  float4 cin = ((const float4*)(C1 + (size_t)a * D))[q];
  float4 c, h;
  lstm_gate4(z[q], z[32 + q], z[64 + q], z[96 + q],
             r[q], r[32 + q], r[64 + q], r[96 + q], cin, &c, &h);
  ((float4*)c2)[idx] = c;
  ((float4*)h2)[idx] = h;
}

// T=3 final: gates = Z[c_node] + R2[p_local]; scatter agg[c_node]
__global__ void lstm_final3(const int* __restrict__ path, const float* __restrict__ Z,
                            const float* __restrict__ R2, const float* __restrict__ c2,
                            float* __restrict__ agg, int n4) {
  int idx = blockIdx.x * blockDim.x + threadIdx.x;
  if (idx >= n4) return;
  int p = idx >> 5, q = idx & 31;
  int cnode = path[p * 3 + 2];
  const float4* z = (const float4*)(Z + (size_t)cnode * G4);
  const float4* r = (const float4*)(R2 + (size_t)p * G4);
  float4 cin = ((const float4*)c2)[idx];
  float4 c, h;
  lstm_gate4(z[q], z[32 + q], z[64 + q], z[96 + q],
             r[q], r[32 + q], r[64 + q], r[96 + q], cin, &c, &h);
  float* dst = agg + (size_t)cnode * D + q * 4;
  atomicAdd(dst + 0, h.x); atomicAdd(dst + 1, h.y);
  atomicAdd(dst + 2, h.z); atomicAdd(dst + 3, h.w);
}

// ---------------------------------------------------------------------------
__global__ void pool_kernel(const float* __restrict__ h, const int* __restrict__ batch,
                            float* __restrict__ pooled, int n4) {
  int idx = blockIdx.x * blockDim.x + threadIdx.x;
  if (idx >= n4) return;
  int v = idx >> 5, q = idx & 31;
  float4 hv = ((const float4*)h)[idx];
  float* dst = pooled + (size_t)batch[v] * D + q * 4;
  atomicAdd(dst + 0, hv.x); atomicAdd(dst + 1, hv.y);
  atomicAdd(dst + 2, hv.z); atomicAdd(dst + 3, hv.w);
}

// ---------------------------------------------------------------------------
extern "C" void kernel_launch(void* const* d_in, const int* in_sizes, int n_in,
                              void* d_out, int out_size, void* d_ws, size_t ws_size,
                              hipStream_t stream) {
  const float* x      = (const float*)d_in[0];
  const int*   path2  = (const int*)d_in[1];
  const int*   path3  = (const int*)d_in[2];
  const int*   batch  = (const int*)d_in[3];
  const float* fe_w1  = (const float*)d_in[4];
  const float* fe_b1  = (const float*)d_in[5];
  const float* fe_g1  = (const float*)d_in[6];
  const float* fe_be1 = (const float*)d_in[7];
  const float* fe_w2  = (const float*)d_in[8];
  const float* fe_b2  = (const float*)d_in[9];
  const float* fe_g2  = (const float*)d_in[10];
  const float* fe_be2 = (const float*)d_in[11];
  const float* w_ih   = (const float*)d_in[12];
  const float* w_hh   = (const float*)d_in[13];
  const float* b_ih   = (const float*)d_in[14];
  const float* b_hh   = (const float*)d_in[15];
  const float* bn1_g  = (const float*)d_in[16];
  const float* bn1_b  = (const float*)d_in[17];
  const float* bn2_g  = (const float*)d_in[18];
  const float* bn2_b  = (const float*)d_in[19];
  const float* lin1_w = (const float*)d_in[20];
  const float* lin1_b = (const float*)d_in[21];
  const float* lin2_w = (const float*)d_in[22];
  const float* lin2_b = (const float*)d_in[23];
  float* out = (float*)d_out;

  float* w = (float*)d_ws;
  float* h    = w; w += (size_t)NN * D;
  float* agg  = w; w += (size_t)NN * D;
  float* Z    = w; w += (size_t)NN * G4;
  float* R1   = w; w += (size_t)NN * G4;
  float* H1   = w; w += (size_t)NN * D;
  float* C1   = w; w += (size_t)NN * D;
  float* h2c  = w; w += (size_t)CHUNK * D;
  float* c2c  = w; w += (size_t)CHUNK * D;
  float* R2c  = w; w += (size_t)CHUNK * G4;
  float* stats  = w; w += 256;
  float* pooled = w; w += (size_t)NG * D;
  float* out1   = w; w += (size_t)NG * D;
  float* bcomb  = w; w += G4;
  float* ency = Z;  // encoder temp reuses Z space

  auto gemm = [&](const float* A, const float* Wm, const float* bias, float* Cm,
                  int M, int N, bool relu) {
    dim3 g((M + 127) / 128, (N + 127) / 128);
    gemm128<<<g, 256, 0, stream>>>(A, Wm, bias, Cm, M, N, relu ? 1 : 0);
  };
  auto bn = [&](const float* u, const float* gamma, const float* beta, float* o, int M) {
    zero_kernel<<<1, 256, 0, stream>>>(stats, 256);
    const int blocks = 160;
    int rows = (M + blocks - 1) / blocks;
    bn_stats<<<blocks, 256, 0, stream>>>(u, stats, M, rows);
    int n4 = M * 32;
    bn_apply_relu<<<(n4 + 255) / 256, 256, 0, stream>>>(u, stats, gamma, beta, o, n4, 1.0f / M);
  };

  addvec_kernel<<<2, 256, 0, stream>>>(b_ih, b_hh, bcomb, G4);

  // ---- feature encoder ----
  gemm(x, fe_w1, fe_b1, ency, NN, D, false);
  bn(ency, fe_g1, fe_be1, h, NN);
  gemm(h, fe_w2, fe_b2, ency, NN, D, false);
  bn(ency, fe_g2, fe_be2, h, NN);

  // ---- PathConv layer 1 (T=2) ----
  gemm(h, w_ih, bcomb, Z, NN, G4, false);
  lstm_step0<<<(NN * 32 + 255) / 256, 256, 0, stream>>>(Z, H1, C1, NN * 32);
  gemm(H1, w_hh, nullptr, R1, NN, G4, false);
  hipMemcpyAsync(agg, h, (size_t)NN * D * sizeof(float), hipMemcpyDeviceToDevice, stream);
  lstm_final2<<<(NP * 32 + 255) / 256, 256, 0, stream>>>(path2, Z, R1, C1, agg, NP * 32);
  bn(agg, bn1_g, bn1_b, h, NN);

  // ---- PathConv layer 2 (T=3) ----
  gemm(h, w_ih, bcomb, Z, NN, G4, false);
  lstm_step0<<<(NN * 32 + 255) / 256, 256, 0, stream>>>(Z, H1, C1, NN * 32);
  gemm(H1, w_hh, nullptr, R1, NN, G4, false);
  hipMemcpyAsync(agg, h, (size_t)NN * D * sizeof(float), hipMemcpyDeviceToDevice, stream);
  for (int p0 = 0; p0 < NP; p0 += CHUNK) {
    int pc = NP - p0 < CHUNK ? NP - p0 : CHUNK;
    int n4 = pc * 32;
    lstm_step1<<<(n4 + 255) / 256, 256, 0, stream>>>(path3 + (size_t)p0 * 3, Z, R1, C1,
                                                     h2c, c2c, n4);
    gemm(h2c, w_hh, nullptr, R2c, pc, G4, false);
    lstm_final3<<<(n4 + 255) / 256, 256, 0, stream>>>(path3 + (size_t)p0 * 3, Z, R2c, c2c,
                                                      agg, n4);
  }
  bn(agg, bn2_g, bn2_b, h, NN);

  // ---- global add pool + MLP head ----
  zero_kernel<<<64, 256, 0, stream>>>(pooled, NG * D);
  pool_kernel<<<(NN * 32 + 255) / 256, 256, 0, stream>>>(h, batch, pooled, NN * 32);
  gemm(pooled, lin1_w, lin1_b, out1, NG, D, true);
  gemm(out1, lin2_w, lin2_b, out, NG, NC, false);
}

// Round 5
// 1248.825 us; speedup vs baseline: 1.2652x; 1.2652x over previous
//
#include <hip/hip_runtime.h>
#include <cmath>

// Problem constants (match reference)
#define NN 20000     // N_NODES
#define NP 100000    // N_PATHS
#define D  128       // D_IN == H
#define G4 512       // 4*H gate width
#define NG 128       // N_GRAPHS
#define NC 10        // N_CLASSES
#define CHUNK 20000  // path_3 processing chunk

__device__ __forceinline__ float sigf(float x) { return 1.0f / (1.0f + expf(-x)); }

// ---------------------------------------------------------------------------
// GEMM: C[M,N] = A[M,128] @ W[N,128]^T (+bias[N]) (optional relu). K=128 fixed.
// 128x128 tile, 256 threads, 8x8/thread. K in two 64-chunks through ONE 64KB
// LDS buffer (2 blocks/CU, 8 waves/CU for cross-block overlap). NO register
// prefetch (round-3 spill bug: liveness ~200 > cap 120 -> scratch).
// LDS float4 slot(r,c4) = r*16 + (c4 ^ ((r>>3)&7)):
//   A-reads: 4 distinct addrs/wave, 16-lane broadcast, disjoint bank spans.
//   W-reads: 16 addrs, 2 per 4-bank span = floor for 256B.
//   Staging writes: 64x16B = 8 bank-rounds = structural floor.
// ---------------------------------------------------------------------------
__device__ __forceinline__ void stage_chunk(
    const float* __restrict__ A, const float* __restrict__ W,
    float4* As4, float4* Ws4, int bm, int bn, int M, int N,
    int koff, int sr, int sc)
{
#pragma unroll
  for (int pass = 0; pass < 8; ++pass) {
    int r = pass * 16 + sr;
    int sw = sc ^ ((r >> 3) & 7);
    int ga = bm + r; ga = ga < M ? ga : M - 1;
    As4[r * 16 + sw] = *(const float4*)(A + (size_t)ga * 128 + koff + sc * 4);
    int gw = bn + r; gw = gw < N ? gw : N - 1;
    Ws4[r * 16 + sw] = *(const float4*)(W + (size_t)gw * 128 + koff + sc * 4);
  }
}

__device__ __forceinline__ void compute_chunk(
    const float4* As4, const float4* Ws4,
    int tm, int tn, int axor, int wxor, float acc[8][8])
{
#pragma unroll 2
  for (int k4 = 0; k4 < 16; ++k4) {
    float4 av[8], wv[8];
#pragma unroll
    for (int i = 0; i < 8; ++i) av[i] = As4[(tm + i) * 16 + (k4 ^ axor)];
#pragma unroll
    for (int j = 0; j < 8; ++j) wv[j] = Ws4[(tn + j) * 16 + (k4 ^ wxor)];
#pragma unroll
    for (int i = 0; i < 8; ++i)
#pragma unroll
      for (int j = 0; j < 8; ++j) {
        acc[i][j] = fmaf(av[i].x, wv[j].x, acc[i][j]);
        acc[i][j] = fmaf(av[i].y, wv[j].y, acc[i][j]);
        acc[i][j] = fmaf(av[i].z, wv[j].z, acc[i][j]);
        acc[i][j] = fmaf(av[i].w, wv[j].w, acc[i][j]);
      }
  }
}

__global__ __launch_bounds__(256) void gemm128(
    const float* __restrict__ A, const float* __restrict__ W,
    const float* __restrict__ bias, float* __restrict__ C,
    int M, int N, int relu)
{
  __shared__ float4 As4[2048];  // 128 rows x 16 float4 (one 64-wide K chunk)
  __shared__ float4 Ws4[2048];

  const int tid = threadIdx.x;
  const int bm = blockIdx.x * 128;
  const int bn = blockIdx.y * 128;

  const int ty = tid >> 4, tx = tid & 15;
  const int tm = ty * 8, tn = tx * 8;
  const int axor = ty & 7, wxor = tx & 7;
  const int sr = tid >> 4, sc = tid & 15;

  float acc[8][8] = {};

  stage_chunk(A, W, As4, Ws4, bm, bn, M, N, 0, sr, sc);
  __syncthreads();
  compute_chunk(As4, Ws4, tm, tn, axor, wxor, acc);
  __syncthreads();
  stage_chunk(A, W, As4, Ws4, bm, bn, M, N, 64, sr, sc);
  __syncthreads();
  compute_chunk(As4, Ws4, tm, tn, axor, wxor, acc);

  // epilogue: float4 stores where aligned & in-bounds
#pragma unroll
  for (int i = 0; i < 8; ++i) {
    int r = bm + tm + i;
    if (r >= M) continue;
    int cbase = bn + tn;
    if (cbase + 7 < N && ((((size_t)r * N + cbase) & 3) == 0)) {
#pragma unroll
      for (int jj = 0; jj < 2; ++jj) {
        float4 v;
        v.x = acc[i][jj * 4 + 0] + (bias ? bias[cbase + jj * 4 + 0] : 0.f);
        v.y = acc[i][jj * 4 + 1] + (bias ? bias[cbase + jj * 4 + 1] : 0.f);
        v.z = acc[i][jj * 4 + 2] + (bias ? bias[cbase + jj * 4 + 2] : 0.f);
        v.w = acc[i][jj * 4 + 3] + (bias ? bias[cbase + jj * 4 + 3] : 0.f);
        if (relu) { v.x = fmaxf(v.x, 0.f); v.y = fmaxf(v.y, 0.f);
                    v.z = fmaxf(v.z, 0.f); v.w = fmaxf(v.w, 0.f); }
        *(float4*)(C + (size_t)r * N + cbase + jj * 4) = v;
      }
    } else {
#pragma unroll
      for (int j = 0; j < 8; ++j) {
        int cn = cbase + j;
        if (cn >= N) continue;
        float v = acc[i][j] + (bias ? bias[cn] : 0.f);
        if (relu) v = fmaxf(v, 0.f);
        C[(size_t)r * N + cn] = v;
      }
    }
  }
}

// ---------------------------------------------------------------------------
// BatchNorm helpers
// ---------------------------------------------------------------------------
__global__ void zero_kernel(float* p, int n) {
  for (int i = blockIdx.x * blockDim.x + threadIdx.x; i < n; i += gridDim.x * blockDim.x)
    p[i] = 0.f;
}

__global__ void zero_int(int* p, int n) {
  for (int i = blockIdx.x * blockDim.x + threadIdx.x; i < n; i += gridDim.x * blockDim.x)
    p[i] = 0;
}

__global__ void addvec_kernel(const float* a, const float* b, float* o, int n) {
  int i = blockIdx.x * blockDim.x + threadIdx.x;
  if (i < n) o[i] = a[i] + b[i];
}

__global__ __launch_bounds__(256) void bn_stats(const float* __restrict__ u,
                                                float* __restrict__ stats,
                                                int M, int rowsPerBlock) {
  __shared__ float sh[512];
  const int j = threadIdx.x & 127;
  const int half = threadIdx.x >> 7;
  int r0 = blockIdx.x * rowsPerBlock;
  int r1 = min(M, r0 + rowsPerBlock);
  float s = 0.f, q = 0.f;
  for (int r = r0 + half; r < r1; r += 2) {
    float v = u[(size_t)r * 128 + j];
    s += v; q += v * v;
  }
  sh[threadIdx.x] = s;
  sh[256 + threadIdx.x] = q;
  __syncthreads();
  if (threadIdx.x < 128) {
    atomicAdd(&stats[j], sh[j] + sh[j + 128]);
    atomicAdd(&stats[128 + j], sh[256 + j] + sh[256 + j + 128]);
  }
}

__global__ void bn_apply_relu(const float* __restrict__ u, const float* __restrict__ stats,
                              const float* __restrict__ g, const float* __restrict__ b,
                              float* __restrict__ out, int n4, float invM) {
  int idx = blockIdx.x * blockDim.x + threadIdx.x;
  if (idx >= n4) return;
  int q = idx & 31;
  float4 uv = ((const float4*)u)[idx];
  float4 sv = ((const float4*)stats)[q];
  float4 qv = ((const float4*)stats)[32 + q];
  float4 gv = ((const float4*)g)[q];
  float4 bv = ((const float4*)b)[q];
  float4 o;
  { float m = sv.x * invM, var = qv.x * invM - m * m;
    o.x = fmaxf(gv.x * (uv.x - m) * rsqrtf(var + 1e-5f) + bv.x, 0.f); }
  { float m = sv.y * invM, var = qv.y * invM - m * m;
    o.y = fmaxf(gv.y * (uv.y - m) * rsqrtf(var + 1e-5f) + bv.y, 0.f); }
  { float m = sv.z * invM, var = qv.z * invM - m * m;
    o.z = fmaxf(gv.z * (uv.z - m) * rsqrtf(var + 1e-5f) + bv.z, 0.f); }
  { float m = sv.w * invM, var = qv.w * invM - m * m;
    o.w = fmaxf(gv.w * (uv.w - m) * rsqrtf(var + 1e-5f) + bv.w, 0.f); }
  ((float4*)out)[idx] = o;
}

// ---------------------------------------------------------------------------
// Counting sort of paths by destination node: hist -> 1-block scan -> scatter.
// ---------------------------------------------------------------------------
__global__ void hist_k(const int* __restrict__ path, int stride, int col, int np,
                       int* __restrict__ cnt) {
  int i = blockIdx.x * blockDim.x + threadIdx.x;
  if (i < np) atomicAdd(&cnt[path[(size_t)i * stride + col]], 1);
}

__global__ __launch_bounds__(256) void scan_bins(const int* __restrict__ cnt,
                                                 int* __restrict__ rp) {
  __shared__ int sh[256];
  const int t = threadIdx.x;
  const int SEG = (NN + 255) / 256;  // 79
  int lo = t * SEG, hi = min(NN, lo + SEG);
  int s = 0;
  for (int i = lo; i < hi; ++i) s += cnt[i];
  sh[t] = s;
  __syncthreads();
  for (int off = 1; off < 256; off <<= 1) {
    int v = (t >= off) ? sh[t - off] : 0;
    __syncthreads();
    sh[t] += v;
    __syncthreads();
  }
  int base = (t == 0) ? 0 : sh[t - 1];
  for (int i = lo; i < hi; ++i) { rp[i] = base; base += cnt[i]; }
  if (t == 0) rp[NN] = sh[255];
}

__global__ void scatter_k(const int* __restrict__ path, int stride, int col, int np,
                          const int* __restrict__ rp, int* __restrict__ cur,
                          int* __restrict__ perm) {
  int i = blockIdx.x * blockDim.x + threadIdx.x;
  if (i < np) {
    int b = path[(size_t)i * stride + col];
    int pos = atomicAdd(&cur[b], 1);
    perm[rp[b] + pos] = i;
  }
}

// ---------------------------------------------------------------------------
// LSTM pieces (gate order i,f,g,o at float4-offsets 0,32,64,96 per node row).
// ---------------------------------------------------------------------------
__global__ void lstm_step0(const float* __restrict__ Z, float* __restrict__ H1,
                           float* __restrict__ C1, int n4) {
  int idx = blockIdx.x * blockDim.x + threadIdx.x;
  if (idx >= n4) return;
  int v = idx >> 5, q = idx & 31;
  const float4* z = (const float4*)(Z + (size_t)v * G4);
  float4 zi = z[q], zg = z[64 + q], zo = z[96 + q];
  float4 c, h;
  c.x = sigf(zi.x) * tanhf(zg.x); h.x = sigf(zo.x) * tanhf(c.x);
  c.y = sigf(zi.y) * tanhf(zg.y); h.y = sigf(zo.y) * tanhf(c.y);
  c.z = sigf(zi.z) * tanhf(zg.z); h.z = sigf(zo.z) * tanhf(c.z);
  c.w = sigf(zi.w) * tanhf(zg.w); h.w = sigf(zo.w) * tanhf(c.w);
  ((float4*)C1)[idx] = c;
  ((float4*)H1)[idx] = h;
}

__device__ __forceinline__ void lstm_gate4(const float4 zi, const float4 zf,
                                           const float4 zg, const float4 zo,
                                           const float4 ri, const float4 rf,
                                           const float4 rg, const float4 ro,
                                           const float4 cin, float4* cout, float4* hout) {
  float c, out;
  c = sigf(zf.x + rf.x) * cin.x + sigf(zi.x + ri.x) * tanhf(zg.x + rg.x);
  out = sigf(zo.x + ro.x) * tanhf(c); cout->x = c; hout->x = out;
  c = sigf(zf.y + rf.y) * cin.y + sigf(zi.y + ri.y) * tanhf(zg.y + rg.y);
  out = sigf(zo.y + ro.y) * tanhf(c); cout->y = c; hout->y = out;
  c = sigf(zf.z + rf.z) * cin.z + sigf(zi.z + ri.z) * tanhf(zg.z + rg.z);
  out = sigf(zo.z + ro.z) * tanhf(c); cout->z = c; hout->z = out;
  c = sigf(zf.w + rf.w) * cin.w + sigf(zi.w + ri.w) * tanhf(zg.w + rg.w);
  out = sigf(zo.w + ro.w) * tanhf(c); cout->w = c; hout->w = out;
}

// T=2: per-node accumulation over CSR range. No atomics; residual h folded in.
// 32 threads per node; Z[node] loaded once.
__global__ __launch_bounds__(256) void final2_sorted(
    const int* __restrict__ perm, const int* __restrict__ rp,
    const int* __restrict__ path, const float* __restrict__ Z,
    const float* __restrict__ R1, const float* __restrict__ C1,
    const float* __restrict__ h, float* __restrict__ agg)
{
  int node = blockIdx.x * 8 + (threadIdx.x >> 5);
  int q = threadIdx.x & 31;
  if (node >= NN) return;
  const float4* z = (const float4*)(Z + (size_t)node * G4);
  float4 zi = z[q], zf = z[32 + q], zg = z[64 + q], zo = z[96 + q];
  float4 acc = ((const float4*)h)[node * 32 + q];
  int e1 = rp[node + 1];
  for (int e = rp[node]; e < e1; ++e) {
    int p = perm[e];
    int a = path[(size_t)p * 2];
    const float4* r = (const float4*)(R1 + (size_t)a * G4);
    float4 cin = ((const float4*)(C1 + (size_t)a * D))[q];
    float4 c, hh;
    lstm_gate4(zi, zf, zg, zo, r[q], r[32 + q], r[64 + q], r[96 + q], cin, &c, &hh);
    acc.x += hh.x; acc.y += hh.y; acc.z += hh.z; acc.w += hh.w;
  }
  ((float4*)agg)[node * 32 + q] = acc;
}

// T=3 middle step over sorted order: h2/c2 stored at sorted-local index.
__global__ void step1_perm(const int* __restrict__ perm, const int* __restrict__ path,
                           const float* __restrict__ Z, const float* __restrict__ R1,
                           const float* __restrict__ C1, float* __restrict__ h2,
                           float* __restrict__ c2, int p0, int n4) {
  int idx = blockIdx.x * blockDim.x + threadIdx.x;
  if (idx >= n4) return;
  int il = idx >> 5, q = idx & 31;
  int p = perm[p0 + il];
  int a = path[(size_t)p * 3 + 0], b = path[(size_t)p * 3 + 1];
  const float4* z = (const float4*)(Z + (size_t)b * G4);
  const float4* r = (const float4*)(R1 + (size_t)a * G4);
  float4 cin = ((const float4*)(C1 + (size_t)a * D))[q];
  float4 c, h;
  lstm_gate4(z[q], z[32 + q], z[64 + q], z[96 + q],
             r[q], r[32 + q], r[64 + q], r[96 + q], cin, &c, &h);
  ((float4*)c2)[idx] = c;
  ((float4*)h2)[idx] = h;
}

// T=3 final: per-node partial accumulation over this chunk's slice of its CSR
// range. agg read-modify-write by the single owning thread group (no atomics).
// R2c/c2c are already in sorted-local order -> no perm needed.
__global__ __launch_bounds__(256) void final3_chunk(
    const int* __restrict__ rp, const float* __restrict__ Z,
    const float* __restrict__ R2c, const float* __restrict__ c2c,
    float* __restrict__ agg, int p0, int pc)
{
  int node = blockIdx.x * 8 + (threadIdx.x >> 5);
  int q = threadIdx.x & 31;
  if (node >= NN) return;
  int lo = max(rp[node], p0), hi = min(rp[node + 1], p0 + pc);
  if (lo >= hi) return;
  const float4* z = (const float4*)(Z + (size_t)node * G4);
  float4 zi = z[q], zf = z[32 + q], zg = z[64 + q], zo = z[96 + q];
  float4 acc = ((const float4*)agg)[node * 32 + q];
  for (int e = lo; e < hi; ++e) {
    int i = e - p0;
    const float4* r = (const float4*)(R2c + (size_t)i * G4);
    float4 cin = ((const float4*)c2c)[i * 32 + q];
    float4 c, hh;
    lstm_gate4(zi, zf, zg, zo, r[q], r[32 + q], r[64 + q], r[96 + q], cin, &c, &hh);
    acc.x += hh.x; acc.y += hh.y; acc.z += hh.z; acc.w += hh.w;
  }
  ((float4*)agg)[node * 32 + q] = acc;
}

// ---------------------------------------------------------------------------
__global__ void pool_kernel(const float* __restrict__ h, const int* __restrict__ batch,
                            float* __restrict__ pooled, int n4) {
  int idx = blockIdx.x * blockDim.x + threadIdx.x;
  if (idx >= n4) return;
  int v = idx >> 5, q = idx & 31;
  float4 hv = ((const float4*)h)[idx];
  float* dst = pooled + (size_t)batch[v] * D + q * 4;
  atomicAdd(dst + 0, hv.x); atomicAdd(dst + 1, hv.y);
  atomicAdd(dst + 2, hv.z); atomicAdd(dst + 3, hv.w);
}

// ---------------------------------------------------------------------------
extern "C" void kernel_launch(void* const* d_in, const int* in_sizes, int n_in,
                              void* d_out, int out_size, void* d_ws, size_t ws_size,
                              hipStream_t stream) {
  const float* x      = (const float*)d_in[0];
  const int*   path2  = (const int*)d_in[1];
  const int*   path3  = (const int*)d_in[2];
  const int*   batch  = (const int*)d_in[3];
  const float* fe_w1  = (const float*)d_in[4];
  const float* fe_b1  = (const float*)d_in[5];
  const float* fe_g1  = (const float*)d_in[6];
  const float* fe_be1 = (const float*)d_in[7];
  const float* fe_w2  = (const float*)d_in[8];
  const float* fe_b2  = (const float*)d_in[9];
  const float* fe_g2  = (const float*)d_in[10];
  const float* fe_be2 = (const float*)d_in[11];
  const float* w_ih   = (const float*)d_in[12];
  const float* w_hh   = (const float*)d_in[13];
  const float* b_ih   = (const float*)d_in[14];
  const float* b_hh   = (const float*)d_in[15];
  const float* bn1_g  = (const float*)d_in[16];
  const float* bn1_b  = (const float*)d_in[17];
  const float* bn2_g  = (const float*)d_in[18];
  const float* bn2_b  = (const float*)d_in[19];
  const float* lin1_w = (const float*)d_in[20];
  const float* lin1_b = (const float*)d_in[21];
  const float* lin2_w = (const float*)d_in[22];
  const float* lin2_b = (const float*)d_in[23];
  float* out = (float*)d_out;

  // workspace carve-up
  float* w = (float*)d_ws;
  float* h    = w; w += (size_t)NN * D;
  float* agg  = w; w += (size_t)NN * D;
  float* Z    = w; w += (size_t)NN * G4;
  float* R1   = w; w += (size_t)NN * G4;
  float* H1   = w; w += (size_t)NN * D;   // aliased as h2c in the chunk loop
  float* C1   = w; w += (size_t)NN * D;
  float* c2c  = w; w += (size_t)CHUNK * D;
  float* R2c  = w; w += (size_t)CHUNK * G4;
  float* stats  = w; w += 256;
  float* pooled = w; w += (size_t)NG * D;
  float* out1   = w; w += (size_t)NG * D;
  float* bcomb  = w; w += G4;
  float* ency = Z;      // encoder temp reuses Z space (Z not live yet)
  float* h2c  = H1;     // H1 dead after R1 gemm

  int* iw = (int*)w;
  int* cnt2  = iw; iw += NN;
  int* cur2  = iw; iw += NN;
  int* rp2   = iw; iw += NN + 1;
  int* perm2 = iw; iw += NP;
  int* cnt3  = iw; iw += NN;
  int* cur3  = iw; iw += NN;
  int* rp3   = iw; iw += NN + 1;
  int* perm3 = iw; iw += NP;

  auto gemm = [&](const float* A, const float* Wm, const float* bias, float* Cm,
                  int M, int N, bool relu) {
    dim3 g((M + 127) / 128, (N + 127) / 128);
    gemm128<<<g, 256, 0, stream>>>(A, Wm, bias, Cm, M, N, relu ? 1 : 0);
  };
  auto bn = [&](const float* u, const float* gamma, const float* beta, float* o, int M) {
    zero_kernel<<<1, 256, 0, stream>>>(stats, 256);
    const int blocks = 160;
    int rows = (M + blocks - 1) / blocks;
    bn_stats<<<blocks, 256, 0, stream>>>(u, stats, M, rows);
    int n4 = M * 32;
    bn_apply_relu<<<(n4 + 255) / 256, 256, 0, stream>>>(u, stats, gamma, beta, o, n4, 1.0f / M);
  };

  // ---- path sorts (independent of features; run first) ----
  zero_int<<<128, 256, 0, stream>>>(cnt2, NN);
  zero_int<<<128, 256, 0, stream>>>(cur2, NN);
  zero_int<<<128, 256, 0, stream>>>(cnt3, NN);
  zero_int<<<128, 256, 0, stream>>>(cur3, NN);
  hist_k<<<(NP + 255) / 256, 256, 0, stream>>>(path2, 2, 1, NP, cnt2);
  hist_k<<<(NP + 255) / 256, 256, 0, stream>>>(path3, 3, 2, NP, cnt3);
  scan_bins<<<1, 256, 0, stream>>>(cnt2, rp2);
  scan_bins<<<1, 256, 0, stream>>>(cnt3, rp3);
  scatter_k<<<(NP + 255) / 256, 256, 0, stream>>>(path2, 2, 1, NP, rp2, cur2, perm2);
  scatter_k<<<(NP + 255) / 256, 256, 0, stream>>>(path3, 3, 2, NP, rp3, cur3, perm3);

  addvec_kernel<<<2, 256, 0, stream>>>(b_ih, b_hh, bcomb, G4);

  // ---- feature encoder ----
  gemm(x, fe_w1, fe_b1, ency, NN, D, false);
  bn(ency, fe_g1, fe_be1, h, NN);
  gemm(h, fe_w2, fe_b2, ency, NN, D, false);
  bn(ency, fe_g2, fe_be2, h, NN);

  // ---- PathConv layer 1 (T=2) ----
  gemm(h, w_ih, bcomb, Z, NN, G4, false);
  lstm_step0<<<(NN * 32 + 255) / 256, 256, 0, stream>>>(Z, H1, C1, NN * 32);
  gemm(H1, w_hh, nullptr, R1, NN, G4, false);
  final2_sorted<<<NN / 8, 256, 0, stream>>>(perm2, rp2, path2, Z, R1, C1, h, agg);
  bn(agg, bn1_g, bn1_b, h, NN);

  // ---- PathConv layer 2 (T=3) ----
  gemm(h, w_ih, bcomb, Z, NN, G4, false);
  lstm_step0<<<(NN * 32 + 255) / 256, 256, 0, stream>>>(Z, H1, C1, NN * 32);
  gemm(H1, w_hh, nullptr, R1, NN, G4, false);
  hipMemcpyAsync(agg, h, (size_t)NN * D * sizeof(float), hipMemcpyDeviceToDevice, stream);
  for (int p0 = 0; p0 < NP; p0 += CHUNK) {
    int pc = NP - p0 < CHUNK ? NP - p0 : CHUNK;
    int n4 = pc * 32;
    step1_perm<<<(n4 + 255) / 256, 256, 0, stream>>>(perm3, path3, Z, R1, C1,
                                                     h2c, c2c, p0, n4);
    gemm(h2c, w_hh, nullptr, R2c, pc, G4, false);
    final3_chunk<<<NN / 8, 256, 0, stream>>>(rp3, Z, R2c, c2c, agg, p0, pc);
  }
  bn(agg, bn2_g, bn2_b, h, NN);

  // ---- global add pool + MLP head ----
  zero_kernel<<<64, 256, 0, stream>>>(pooled, NG * D);
  pool_kernel<<<(NN * 32 + 255) / 256, 256, 0, stream>>>(h, batch, pooled, NN * 32);
  gemm(pooled, lin1_w, lin1_b, out1, NG, D, true);
  gemm(out1, lin2_w, lin2_b, out, NG, NC, false);
}

// Round 12
// 1143.568 us; speedup vs baseline: 1.3817x; 1.0920x over previous
//
#include <hip/hip_runtime.h>
#include <cmath>

// Problem constants (match reference)
#define NN 20000     // N_NODES
#define NP 100000    // N_PATHS
#define D  128       // D_IN == H
#define G4 512       // 4*H gate width
#define NG 128       // N_GRAPHS
#define NC 10        // N_CLASSES

// Fast gate math: __expf -> v_exp_f32, __fdividef -> v_rcp_f32.
// libm expf/tanhf are multi-instr range-reduced calls — 63% VALUBusy in r5.
__device__ __forceinline__ float fsig(float x) {
  return __fdividef(1.f, 1.f + __expf(-x));
}
__device__ __forceinline__ float ftanh(float x) {
  float t = __expf(-2.f * fabsf(x));
  return copysignf(__fdividef(1.f - t, 1.f + t), x);
}

// ---------------------------------------------------------------------------
// GEMM: C[M,N] = A[M,128] @ W[N,128]^T (+bias[N]) (optional relu). K=128 fixed.
// 128x128 tile, 256 threads, 8x8/thread. Two 64-wide K chunks through one
// 64KB LDS buffer (2 blocks/CU). No register prefetch (r3 spill lesson).
// ---------------------------------------------------------------------------
__device__ __forceinline__ void stage_chunk(
    const float* __restrict__ A, const float* __restrict__ W,
    float4* As4, float4* Ws4, int bm, int bn, int M, int N,
    int koff, int sr, int sc)
{
#pragma unroll
  for (int pass = 0; pass < 8; ++pass) {
    int r = pass * 16 + sr;
    int sw = sc ^ ((r >> 3) & 7);
    int ga = bm + r; ga = ga < M ? ga : M - 1;
    As4[r * 16 + sw] = *(const float4*)(A + (size_t)ga * 128 + koff + sc * 4);
    int gw = bn + r; gw = gw < N ? gw : N - 1;
    Ws4[r * 16 + sw] = *(const float4*)(W + (size_t)gw * 128 + koff + sc * 4);
  }
}

__device__ __forceinline__ void compute_chunk(
    const float4* As4, const float4* Ws4,
    int tm, int tn, int axor, int wxor, float acc[8][8])
{
#pragma unroll 2
  for (int k4 = 0; k4 < 16; ++k4) {
    float4 av[8], wv[8];
#pragma unroll
    for (int i = 0; i < 8; ++i) av[i] = As4[(tm + i) * 16 + (k4 ^ axor)];
#pragma unroll
    for (int j = 0; j < 8; ++j) wv[j] = Ws4[(tn + j) * 16 + (k4 ^ wxor)];
#pragma unroll
    for (int i = 0; i < 8; ++i)
#pragma unroll
      for (int j = 0; j < 8; ++j) {
        acc[i][j] = fmaf(av[i].x, wv[j].x, acc[i][j]);
        acc[i][j] = fmaf(av[i].y, wv[j].y, acc[i][j]);
        acc[i][j] = fmaf(av[i].z, wv[j].z, acc[i][j]);
        acc[i][j] = fmaf(av[i].w, wv[j].w, acc[i][j]);
      }
  }
}

__global__ __launch_bounds__(256) void gemm128(
    const float* __restrict__ A, const float* __restrict__ W,
    const float* __restrict__ bias, float* __restrict__ C,
    int M, int N, int relu)
{
  __shared__ float4 As4[2048];
  __shared__ float4 Ws4[2048];

  const int tid = threadIdx.x;
  const int bm = blockIdx.x * 128;
  const int bn = blockIdx.y * 128;

  const int ty = tid >> 4, tx = tid & 15;
  const int tm = ty * 8, tn = tx * 8;
  const int axor = ty & 7, wxor = tx & 7;
  const int sr = tid >> 4, sc = tid & 15;

  float acc[8][8] = {};

  stage_chunk(A, W, As4, Ws4, bm, bn, M, N, 0, sr, sc);
  __syncthreads();
  compute_chunk(As4, Ws4, tm, tn, axor, wxor, acc);
  __syncthreads();
  stage_chunk(A, W, As4, Ws4, bm, bn, M, N, 64, sr, sc);
  __syncthreads();
  compute_chunk(As4, Ws4, tm, tn, axor, wxor, acc);

#pragma unroll
  for (int i = 0; i < 8; ++i) {
    int r = bm + tm + i;
    if (r >= M) continue;
    int cbase = bn + tn;
    if (cbase + 7 < N && ((((size_t)r * N + cbase) & 3) == 0)) {
#pragma unroll
      for (int jj = 0; jj < 2; ++jj) {
        float4 v;
        v.x = acc[i][jj * 4 + 0] + (bias ? bias[cbase + jj * 4 + 0] : 0.f);
        v.y = acc[i][jj * 4 + 1] + (bias ? bias[cbase + jj * 4 + 1] : 0.f);
        v.z = acc[i][jj * 4 + 2] + (bias ? bias[cbase + jj * 4 + 2] : 0.f);
        v.w = acc[i][jj * 4 + 3] + (bias ? bias[cbase + jj * 4 + 3] : 0.f);
        if (relu) { v.x = fmaxf(v.x, 0.f); v.y = fmaxf(v.y, 0.f);
                    v.z = fmaxf(v.z, 0.f); v.w = fmaxf(v.w, 0.f); }
        *(float4*)(C + (size_t)r * N + cbase + jj * 4) = v;
      }
    } else {
#pragma unroll
      for (int j = 0; j < 8; ++j) {
        int cn = cbase + j;
        if (cn >= N) continue;
        float v = acc[i][j] + (bias ? bias[cn] : 0.f);
        if (relu) v = fmaxf(v, 0.f);
        C[(size_t)r * N + cn] = v;
      }
    }
  }
}

// ---------------------------------------------------------------------------
// Helpers
// ---------------------------------------------------------------------------
__global__ void zero_kernel(float* p, int n) {
  for (int i = blockIdx.x * blockDim.x + threadIdx.x; i < n; i += gridDim.x * blockDim.x)
    p[i] = 0.f;
}

__global__ void zero_int(int* p, int n) {
  for (int i = blockIdx.x * blockDim.x + threadIdx.x; i < n; i += gridDim.x * blockDim.x)
    p[i] = 0;
}

__global__ void addvec_kernel(const float* a, const float* b, float* o, int n) {
  int i = blockIdx.x * blockDim.x + threadIdx.x;
  if (i < n) o[i] = a[i] + b[i];
}

__global__ __launch_bounds__(256) void bn_stats(const float* __restrict__ u,
                                                float* __restrict__ stats,
                                                int M, int rowsPerBlock) {
  __shared__ float sh[512];
  const int j = threadIdx.x & 127;
  const int half = threadIdx.x >> 7;
  int r0 = blockIdx.x * rowsPerBlock;
  int r1 = min(M, r0 + rowsPerBlock);
  float s = 0.f, q = 0.f;
  for (int r = r0 + half; r < r1; r += 2) {
    float v = u[(size_t)r * 128 + j];
    s += v; q += v * v;
  }
  sh[threadIdx.x] = s;
  sh[256 + threadIdx.x] = q;
  __syncthreads();
  if (threadIdx.x < 128) {
    atomicAdd(&stats[j], sh[j] + sh[j + 128]);
    atomicAdd(&stats[128 + j], sh[256 + j] + sh[256 + j + 128]);
  }
}

__global__ void bn_apply_relu(const float* __restrict__ u, const float* __restrict__ stats,
                              const float* __restrict__ g, const float* __restrict__ b,
                              float* __restrict__ out, int n4, float invM) {
  int idx = blockIdx.x * blockDim.x + threadIdx.x;
  if (idx >= n4) return;
  int q = idx & 31;
  float4 uv = ((const float4*)u)[idx];
  float4 sv = ((const float4*)stats)[q];
  float4 qv = ((const float4*)stats)[32 + q];
  float4 gv = ((const float4*)g)[q];
  float4 bv = ((const float4*)b)[q];
  float4 o;
  { float m = sv.x * invM, var = qv.x * invM - m * m;
    o.x = fmaxf(gv.x * (uv.x - m) * rsqrtf(var + 1e-5f) + bv.x, 0.f); }
  { float m = sv.y * invM, var = qv.y * invM - m * m;
    o.y = fmaxf(gv.y * (uv.y - m) * rsqrtf(var + 1e-5f) + bv.y, 0.f); }
  { float m = sv.z * invM, var = qv.z * invM - m * m;
    o.z = fmaxf(gv.z * (uv.z - m) * rsqrtf(var + 1e-5f) + bv.z, 0.f); }
  { float m = sv.w * invM, var = qv.w * invM - m * m;
    o.w = fmaxf(gv.w * (uv.w - m) * rsqrtf(var + 1e-5f) + bv.w, 0.f); }
  ((float4*)out)[idx] = o;
}

// ---------------------------------------------------------------------------
// Counting sort by destination; scatter stores the GATHERED COLUMNS directly
// (a2s / ab3) so edge loops have no perm->path dependent-load chain.
// ---------------------------------------------------------------------------
__global__ void hist_k(const int* __restrict__ path, int stride, int col, int np,
                       int* __restrict__ cnt) {
  int i = blockIdx.x * blockDim.x + threadIdx.x;
  if (i < np) atomicAdd(&cnt[path[(size_t)i * stride + col]], 1);
}

__global__ __launch_bounds__(256) void scan_bins(const int* __restrict__ cnt,
                                                 int* __restrict__ rp) {
  __shared__ int sh[256];
  const int t = threadIdx.x;
  const int SEG = (NN + 255) / 256;
  int lo = t * SEG, hi = min(NN, lo + SEG);
  int s = 0;
  for (int i = lo; i < hi; ++i) s += cnt[i];
  sh[t] = s;
  __syncthreads();
  for (int off = 1; off < 256; off <<= 1) {
    int v = (t >= off) ? sh[t - off] : 0;
    __syncthreads();
    sh[t] += v;
    __syncthreads();
  }
  int base = (t == 0) ? 0 : sh[t - 1];
  for (int i = lo; i < hi; ++i) { rp[i] = base; base += cnt[i]; }
  if (t == 0) rp[NN] = sh[255];
}

__global__ void scatter2(const int* __restrict__ path, int np,
                         const int* __restrict__ rp, int* __restrict__ cur,
                         int* __restrict__ a2s) {
  int i = blockIdx.x * blockDim.x + threadIdx.x;
  if (i < np) {
    int b = path[(size_t)i * 2 + 1];
    int pos = rp[b] + atomicAdd(&cur[b], 1);
    a2s[pos] = path[(size_t)i * 2];
  }
}

__global__ void scatter3(const int* __restrict__ path, int np,
                         const int* __restrict__ rp, int* __restrict__ cur,
                         int2* __restrict__ ab3) {
  int i = blockIdx.x * blockDim.x + threadIdx.x;
  if (i < np) {
    int c = path[(size_t)i * 3 + 2];
    int pos = rp[c] + atomicAdd(&cur[c], 1);
    ab3[pos] = make_int2(path[(size_t)i * 3], path[(size_t)i * 3 + 1]);
  }
}

// ---------------------------------------------------------------------------
// LSTM pieces (gate order i,f,g,o at float4-offsets 0,32,64,96).
// ---------------------------------------------------------------------------
__global__ void lstm_step0(const float* __restrict__ Z, float* __restrict__ H1,
                           float* __restrict__ C1, int n4) {
  int idx = blockIdx.x * blockDim.x + threadIdx.x;
  if (idx >= n4) return;
  int v = idx >> 5, q = idx & 31;
  const float4* z = (const float4*)(Z + (size_t)v * G4);
  float4 zi = z[q], zg = z[64 + q], zo = z[96 + q];
  float4 c, h;
  c.x = fsig(zi.x) * ftanh(zg.x); h.x = fsig(zo.x) * ftanh(c.x);
  c.y = fsig(zi.y) * ftanh(zg.y); h.y = fsig(zo.y) * ftanh(c.y);
  c.z = fsig(zi.z) * ftanh(zg.z); h.z = fsig(zo.z) * ftanh(c.z);
  c.w = fsig(zi.w) * ftanh(zg.w); h.w = fsig(zo.w) * ftanh(c.w);
  ((float4*)C1)[idx] = c;
  ((float4*)H1)[idx] = h;
}

__device__ __forceinline__ void lstm_gate4(const float4 zi, const float4 zf,
                                           const float4 zg, const float4 zo,
                                           const float4 ri, const float4 rf,
                                           const float4 rg, const float4 ro,
                                           const float4 cin, float4* cout, float4* hout) {
  float c;
  c = fsig(zf.x + rf.x) * cin.x + fsig(zi.x + ri.x) * ftanh(zg.x + rg.x);
  cout->x = c; hout->x = fsig(zo.x + ro.x) * ftanh(c);
  c = fsig(zf.y + rf.y) * cin.y + fsig(zi.y + ri.y) * ftanh(zg.y + rg.y);
  cout->y = c; hout->y = fsig(zo.y + ro.y) * ftanh(c);
  c = fsig(zf.z + rf.z) * cin.z + fsig(zi.z + ri.z) * ftanh(zg.z + rg.z);
  cout->z = c; hout->z = fsig(zo.z + ro.z) * ftanh(c);
  c = fsig(zf.w + rf.w) * cin.w + fsig(zi.w + ri.w) * ftanh(zg.w + rg.w);
  cout->w = c; hout->w = fsig(zo.w + ro.w) * ftanh(c);
}

// T=2: per-node accumulation over CSR range; a-index comes straight from a2s.
__global__ __launch_bounds__(256) void final2_sorted(
    const int* __restrict__ a2s, const int* __restrict__ rp,
    const float* __restrict__ Z, const float* __restrict__ R1,
    const float* __restrict__ C1, const float* __restrict__ h,
    float* __restrict__ agg)
{
  int node = blockIdx.x * 8 + (threadIdx.x >> 5);
  int q = threadIdx.x & 31;
  if (node >= NN) return;
  const float4* z = (const float4*)(Z + (size_t)node * G4);
  float4 zi = z[q], zf = z[32 + q], zg = z[64 + q], zo = z[96 + q];
  float4 acc = ((const float4*)h)[node * 32 + q];
  int e0 = rp[node], e1 = rp[node + 1];
  for (int e = e0; e < e1; ++e) {
    int a = a2s[e];
    const float4* r = (const float4*)(R1 + (size_t)a * G4);
    float4 cin = ((const float4*)(C1 + (size_t)a * D))[q];
    float4 c, hh;
    lstm_gate4(zi, zf, zg, zo, r[q], r[32 + q], r[64 + q], r[96 + q], cin, &c, &hh);
    acc.x += hh.x; acc.y += hh.y; acc.z += hh.z; acc.w += hh.w;
  }
  ((float4*)agg)[node * 32 + q] = acc;
}

// T=3 middle: edge-parallel in c-sorted order, (a,b) from ab3.
__global__ void step1_sorted(const int2* __restrict__ ab3,
                             const float* __restrict__ Z, const float* __restrict__ R1,
                             const float* __restrict__ C1, float* __restrict__ h2,
                             float* __restrict__ c2, int p0, int n4) {
  int idx = blockIdx.x * blockDim.x + threadIdx.x;
  if (idx >= n4) return;
  int il = idx >> 5, q = idx & 31;
  int2 ab = ab3[p0 + il];
  const float4* z = (const float4*)(Z + (size_t)ab.y * G4);
  const float4* r = (const float4*)(R1 + (size_t)ab.x * G4);
  float4 cin = ((const float4*)(C1 + (size_t)ab.x * D))[q];
  float4 c, h;
  lstm_gate4(z[q], z[32 + q], z[64 + q], z[96 + q],
             r[q], r[32 + q], r[64 + q], r[96 + q], cin, &c, &h);
  ((float4*)c2)[idx] = c;
  ((float4*)h2)[idx] = h;
}

// T=3 final: per-node accumulation over this chunk's slice (sequential R2c/c2c).
__global__ __launch_bounds__(256) void final3_chunk(
    const int* __restrict__ rp, const float* __restrict__ Z,
    const float* __restrict__ R2c, const float* __restrict__ c2c,
    float* __restrict__ agg, int p0, int pc)
{
  int node = blockIdx.x * 8 + (threadIdx.x >> 5);
  int q = threadIdx.x & 31;
  if (node >= NN) return;
  int lo = max(rp[node], p0), hi = min(rp[node + 1], p0 + pc);
  if (lo >= hi) return;
  const float4* z = (const float4*)(Z + (size_t)node * G4);
  float4 zi = z[q], zf = z[32 + q], zg = z[64 + q], zo = z[96 + q];
  float4 acc = ((const float4*)agg)[node * 32 + q];
  for (int e = lo; e < hi; ++e) {
    int i = e - p0;
    const float4* r = (const float4*)(R2c + (size_t)i * G4);
    float4 cin = ((const float4*)c2c)[i * 32 + q];
    float4 c, hh;
    lstm_gate4(zi, zf, zg, zo, r[q], r[32 + q], r[64 + q], r[96 + q], cin, &c, &hh);
    acc.x += hh.x; acc.y += hh.y; acc.z += hh.z; acc.w += hh.w;
  }
  ((float4*)agg)[node * 32 + q] = acc;
}

// ---------------------------------------------------------------------------
__global__ void pool_kernel(const float* __restrict__ h, const int* __restrict__ batch,
                            float* __restrict__ pooled, int n4) {
  int idx = blockIdx.x * blockDim.x + threadIdx.x;
  if (idx >= n4) return;
  int v = idx >> 5, q = idx & 31;
  float4 hv = ((const float4*)h)[idx];
  float* dst = pooled + (size_t)batch[v] * D + q * 4;
  atomicAdd(dst + 0, hv.x); atomicAdd(dst + 1, hv.y);
  atomicAdd(dst + 2, hv.z); atomicAdd(dst + 3, hv.w);
}

// ---------------------------------------------------------------------------
extern "C" void kernel_launch(void* const* d_in, const int* in_sizes, int n_in,
                              void* d_out, int out_size, void* d_ws, size_t ws_size,
                              hipStream_t stream) {
  const float* x      = (const float*)d_in[0];
  const int*   path2  = (const int*)d_in[1];
  const int*   path3  = (const int*)d_in[2];
  const int*   batch  = (const int*)d_in[3];
  const float* fe_w1  = (const float*)d_in[4];
  const float* fe_b1  = (const float*)d_in[5];
  const float* fe_g1  = (const float*)d_in[6];
  const float* fe_be1 = (const float*)d_in[7];
  const float* fe_w2  = (const float*)d_in[8];
  const float* fe_b2  = (const float*)d_in[9];
  const float* fe_g2  = (const float*)d_in[10];
  const float* fe_be2 = (const float*)d_in[11];
  const float* w_ih   = (const float*)d_in[12];
  const float* w_hh   = (const float*)d_in[13];
  const float* b_ih   = (const float*)d_in[14];
  const float* b_hh   = (const float*)d_in[15];
  const float* bn1_g  = (const float*)d_in[16];
  const float* bn1_b  = (const float*)d_in[17];
  const float* bn2_g  = (const float*)d_in[18];
  const float* bn2_b  = (const float*)d_in[19];
  const float* lin1_w = (const float*)d_in[20];
  const float* lin1_b = (const float*)d_in[21];
  const float* lin2_w = (const float*)d_in[22];
  const float* lin2_b = (const float*)d_in[23];
  float* out = (float*)d_out;

  // ---- workspace carve-up (persistent) ----
  float* w = (float*)d_ws;
  float* h    = w; w += (size_t)NN * D;
  float* agg  = w; w += (size_t)NN * D;
  float* Z    = w; w += (size_t)NN * G4;
  float* R1   = w; w += (size_t)NN * G4;
  float* H1   = w; w += (size_t)NN * D;
  float* C1   = w; w += (size_t)NN * D;
  float* stats  = w; w += 256;
  float* pooled = w; w += (size_t)NG * D;
  float* out1   = w; w += (size_t)NG * D;
  float* bcomb  = w; w += G4;
  float* ency = Z;   // encoder temp reuses Z space (Z not live yet)

  int2* ab3 = (int2*)(((uintptr_t)w + 7) & ~(uintptr_t)7);
  int* iw = (int*)(ab3 + NP);
  int* a2s  = iw; iw += NP;
  int* cnt2 = iw; iw += NN;
  int* cur2 = iw; iw += NN;
  int* rp2  = iw; iw += NN + 1;
  int* cnt3 = iw; iw += NN;
  int* cur3 = iw; iw += NN;
  int* rp3  = iw; iw += NN + 1;

  // ---- dynamic chunk buffers from remaining workspace ----
  float* cb = (float*)(((uintptr_t)iw + 15) & ~(uintptr_t)15);
  size_t used = (char*)cb - (char*)d_ws;
  size_t remf = (ws_size > used) ? (ws_size - used) / 4 : 0;
  int chunk = (int)((remf / 768 > (size_t)NP) ? (size_t)NP : remf / 768);
  chunk &= ~63;
  if (chunk < 64) chunk = 64;  // degenerate-ws fallback
  float* h2c = cb;
  float* c2c = h2c + (size_t)chunk * D;
  float* R2c = c2c + (size_t)chunk * D;

  auto gemm = [&](const float* A, const float* Wm, const float* bias, float* Cm,
                  int M, int N, bool relu) {
    dim3 g((M + 127) / 128, (N + 127) / 128);
    gemm128<<<g, 256, 0, stream>>>(A, Wm, bias, Cm, M, N, relu ? 1 : 0);
  };
  auto bn = [&](const float* u, const float* gamma, const float* beta, float* o, int M) {
    zero_kernel<<<1, 256, 0, stream>>>(stats, 256);
    const int blocks = 160;
    int rows = (M + blocks - 1) / blocks;
    bn_stats<<<blocks, 256, 0, stream>>>(u, stats, M, rows);
    int n4 = M * 32;
    bn_apply_relu<<<(n4 + 255) / 256, 256, 0, stream>>>(u, stats, gamma, beta, o, n4, 1.0f / M);
  };

  // ---- path sorts (independent of features; run first) ----
  zero_int<<<128, 256, 0, stream>>>(cnt2, NN);
  zero_int<<<128, 256, 0, stream>>>(cur2, NN);
  zero_int<<<128, 256, 0, stream>>>(cnt3, NN);
  zero_int<<<128, 256, 0, stream>>>(cur3, NN);
  hist_k<<<(NP + 255) / 256, 256, 0, stream>>>(path2, 2, 1, NP, cnt2);
  hist_k<<<(NP + 255) / 256, 256, 0, stream>>>(path3, 3, 2, NP, cnt3);
  scan_bins<<<1, 256, 0, stream>>>(cnt2, rp2);
  scan_bins<<<1, 256, 0, stream>>>(cnt3, rp3);
  scatter2<<<(NP + 255) / 256, 256, 0, stream>>>(path2, NP, rp2, cur2, a2s);
  scatter3<<<(NP + 255) / 256, 256, 0, stream>>>(path3, NP, rp3, cur3, ab3);

  addvec_kernel<<<2, 256, 0, stream>>>(b_ih, b_hh, bcomb, G4);

  // ---- feature encoder ----
  gemm(x, fe_w1, fe_b1, ency, NN, D, false);
  bn(ency, fe_g1, fe_be1, h, NN);
  gemm(h, fe_w2, fe_b2, ency, NN, D, false);
  bn(ency, fe_g2, fe_be2, h, NN);

  // ---- PathConv layer 1 (T=2) ----
  gemm(h, w_ih, bcomb, Z, NN, G4, false);
  lstm_step0<<<(NN * 32 + 255) / 256, 256, 0, stream>>>(Z, H1, C1, NN * 32);
  gemm(H1, w_hh, nullptr, R1, NN, G4, false);
  final2_sorted<<<NN / 8, 256, 0, stream>>>(a2s, rp2, Z, R1, C1, h, agg);
  bn(agg, bn1_g, bn1_b, h, NN);

  // ---- PathConv layer 2 (T=3) ----
  gemm(h, w_ih, bcomb, Z, NN, G4, false);
  lstm_step0<<<(NN * 32 + 255) / 256, 256, 0, stream>>>(Z, H1, C1, NN * 32);
  gemm(H1, w_hh, nullptr, R1, NN, G4, false);
  hipMemcpyAsync(agg, h, (size_t)NN * D * sizeof(float), hipMemcpyDeviceToDevice, stream);
  for (int p0 = 0; p0 < NP; p0 += chunk) {
    int pc = NP - p0 < chunk ? NP - p0 : chunk;
    int n4 = pc * 32;
    step1_sorted<<<(n4 + 255) / 256, 256, 0, stream>>>(ab3, Z, R1, C1, h2c, c2c, p0, n4);
    gemm(h2c, w_hh, nullptr, R2c, pc, G4, false);
    final3_chunk<<<NN / 8, 256, 0, stream>>>(rp3, Z, R2c, c2c, agg, p0, pc);
  }
  bn(agg, bn2_g, bn2_b, h, NN);

  // ---- global add pool + MLP head ----
  zero_kernel<<<64, 256, 0, stream>>>(pooled, NG * D);
  pool_kernel<<<(NN * 32 + 255) / 256, 256, 0, stream>>>(h, batch, pooled, NN * 32);
  gemm(pooled, lin1_w, lin1_b, out1, NG, D, true);
  gemm(out1, lin2_w, lin2_b, out, NG, NC, false);
}